// Round 3
// baseline (64732.770 us; speedup 1.0000x reference)
//
#include <hip/hip_runtime.h>
#include <stdint.h>

// ---------------- constants ----------------
#define T_STEPS 1000
#define BATCHN  4096
#define SDIM    128
#define ADIM    32
#define HID     256
#define TDIM    16
#define CONC    (ADIM + TDIM + SDIM)   // 176

// ---------------- threefry2x32 (exact JAX semantics) ----------------
__device__ __forceinline__ uint32_t rotl32(uint32_t v, int d) {
  return (v << d) | (v >> (32 - d));
}

__device__ __forceinline__ void threefry2x32(uint32_t k0, uint32_t k1,
                                             uint32_t x0, uint32_t x1,
                                             uint32_t& o0, uint32_t& o1) {
  uint32_t ks0 = k0, ks1 = k1, ks2 = k0 ^ k1 ^ 0x1BD11BDAu;
  x0 += ks0; x1 += ks1;
#define TF_ROUND(r) { x0 += x1; x1 = rotl32(x1, (r)); x1 ^= x0; }
  TF_ROUND(13) TF_ROUND(15) TF_ROUND(26) TF_ROUND(6)
  x0 += ks1; x1 += ks2 + 1u;
  TF_ROUND(17) TF_ROUND(29) TF_ROUND(16) TF_ROUND(24)
  x0 += ks2; x1 += ks0 + 2u;
  TF_ROUND(13) TF_ROUND(15) TF_ROUND(26) TF_ROUND(6)
  x0 += ks0; x1 += ks1 + 3u;
  TF_ROUND(17) TF_ROUND(29) TF_ROUND(16) TF_ROUND(24)
  x0 += ks1; x1 += ks2 + 4u;
  TF_ROUND(13) TF_ROUND(15) TF_ROUND(26) TF_ROUND(6)
  x0 += ks2; x1 += ks0 + 5u;
#undef TF_ROUND
  o0 = x0; o1 = x1;
}

// JAX partitionable threefry random_bits, bit_width=32:
//   counts = iota(u64); bits1, bits2 = threefry2x32(key, (hi32, lo32))
//   draw   = convert_element_type(bits1 ^ bits2, uint32)   <-- XOR combine
__device__ __forceinline__ uint32_t random_bits32_partitionable(uint32_t k0, uint32_t k1,
                                                               uint32_t j) {
  uint32_t o0, o1;
  threefry2x32(k0, k1, 0u, j, o0, o1);
  return o0 ^ o1;
}

// ---------------- XLA ErfInv (f32 Giles polynomial) ----------------
__device__ __forceinline__ float erfinv_f32(float x) {
  float w = -log1pf(-(x * x));
  float p;
  if (w < 5.0f) {
    w = w - 2.5f;
    p = 2.81022636e-08f;
    p = fmaf(p, w, 3.43273939e-07f);
    p = fmaf(p, w, -3.5233877e-06f);
    p = fmaf(p, w, -4.39150654e-06f);
    p = fmaf(p, w, 0.00021858087f);
    p = fmaf(p, w, -0.00125372503f);
    p = fmaf(p, w, -0.00417768164f);
    p = fmaf(p, w, 0.246640727f);
    p = fmaf(p, w, 1.50140941f);
  } else {
    w = sqrtf(w) - 3.0f;
    p = -0.000200214257f;
    p = fmaf(p, w, 0.000100950558f);
    p = fmaf(p, w, 0.00134934322f);
    p = fmaf(p, w, -0.00367342844f);
    p = fmaf(p, w, 0.00573950773f);
    p = fmaf(p, w, -0.0076224613f);
    p = fmaf(p, w, 0.00943887047f);
    p = fmaf(p, w, 1.00167406f);
    p = fmaf(p, w, 2.83297682f);
  }
  return p * x;
}

// bits -> N(0,1) exactly as jax.random.normal (threefry path)
__device__ __forceinline__ float bits_to_normal(uint32_t bits) {
  float f = __uint_as_float((bits >> 9) | 0x3F800000u) - 1.0f;   // [0,1)
  // minval = nextafter(-1,0) = -0.99999994; (maxval-minval) rounds to exactly 2.0f
  float u = f * 2.0f + (-0.99999994f);
  u = fmaxf(-0.99999994f, u);
  return 1.41421356237309515f * erfinv_f32(u);   // sqrt(2) as f32
}

// mish(x) = x * tanh(softplus(x)); jax softplus = logaddexp(x, 0)
__device__ __forceinline__ float mish_f(float x) {
  float sp = fmaxf(x, 0.0f) + log1pf(expf(-fabsf(x)));
  return x * tanhf(sp);
}

// ---------------- precompute: tf_all[1000][16], coefs[5][1000], keys[1000][2] --------
__global__ __launch_bounds__(64)
void precompute_kernel(const float* __restrict__ w_t1, const float* __restrict__ b_t1,
                       const float* __restrict__ w_t2, const float* __restrict__ b_t2,
                       float* __restrict__ tf_all, float* __restrict__ coefs,
                       uint32_t* __restrict__ keys) {
  const int i = blockIdx.x;
  const int j = threadIdx.x;
  const float tv = (float)i;
  __shared__ float hid[32];
  // freqs scale: -log(10000)/7 in f64, cast f32 (matches numpy scalar -> f32)
  const float CF = (float)(-1.3157629102823120);
  if (j < 32) {
    float acc = b_t1[j];
#pragma unroll
    for (int k = 0; k < 16; ++k) {
      int kf = (k < 8) ? k : (k - 8);
      float fr = expf((float)kf * CF);
      float ang = tv * fr;
      float te = (k < 8) ? sinf(ang) : cosf(ang);
      acc = fmaf(te, w_t1[k * 32 + j], acc);
    }
    hid[j] = mish_f(acc);
  }
  __syncthreads();
  if (j < 16) {
    float acc = b_t2[j];
#pragma unroll
    for (int k2 = 0; k2 < 32; ++k2) acc = fmaf(hid[k2], w_t2[k2 * 16 + j], acc);
    tf_all[i * TDIM + j] = acc;
  }
  if (j == 0) {
    // closed-form vp schedule in f64 (alphas == alpha; ac = cumprod(alpha))
    double t = (double)(i + 1);
    double ac  = exp(-0.1 * t / 1000.0 - 4.95 * t * t / 1.0e6);
    double acp = (i == 0) ? 1.0
        : exp(-0.1 * (t - 1.0) / 1000.0 - 4.95 * (t - 1.0) * (t - 1.0) / 1.0e6);
    double alpha = exp(-0.1 / 1000.0 - 4.95 * (2.0 * t - 1.0) / 1.0e6);
    double beta = 1.0 - alpha;
    double sr   = sqrt(1.0 / ac);
    double srm1 = sqrt(1.0 / ac - 1.0);
    double c1 = beta * sqrt(acp) / (1.0 - ac);
    double c2 = (1.0 - acp) * sqrt(alpha) / (1.0 - ac);
    double pv = beta * (1.0 - acp) / (1.0 - ac);
    double lv = log(fmax(pv, 1.0e-20));
    coefs[0 * T_STEPS + i] = (float)sr;
    coefs[1 * T_STEPS + i] = (float)srm1;
    coefs[2 * T_STEPS + i] = (float)c1;
    coefs[3 * T_STEPS + i] = (float)c2;
    float lvf = (float)lv;
    coefs[4 * T_STEPS + i] = expf(0.5f * lvf);      // sigma in f32 like the reference
    // fold_in(key(1), i) = threefry2x32((0,1), (0,i))  [key-level op: version-stable]
    uint32_t o0, o1;
    threefry2x32(0u, 1u, 0u, (uint32_t)i, o0, o1);
    keys[2 * i]     = o0;
    keys[2 * i + 1] = o1;
  }
}

// ---------------- dense layer: thread j = neuron j, 16 rows in registers -----------
template <int K, bool MISH>
__device__ __forceinline__ void dense_layer(const float* __restrict__ W,
                                            const float* __restrict__ bias,
                                            const float* src, int sstride,
                                            float* dst, int tid) {
  float acc[16];
#pragma unroll
  for (int r = 0; r < 16; ++r) acc[r] = 0.0f;
  for (int k = 0; k < K; k += 4) {
    float w0 = W[(k + 0) * HID + tid];
    float w1 = W[(k + 1) * HID + tid];
    float w2 = W[(k + 2) * HID + tid];
    float w3 = W[(k + 3) * HID + tid];
#pragma unroll
    for (int r = 0; r < 16; ++r) {
      float4 v = *reinterpret_cast<const float4*>(&src[r * sstride + k]);
      acc[r] = fmaf(v.x, w0, acc[r]);
      acc[r] = fmaf(v.y, w1, acc[r]);
      acc[r] = fmaf(v.z, w2, acc[r]);
      acc[r] = fmaf(v.w, w3, acc[r]);
    }
  }
  float b = bias[tid];
#pragma unroll
  for (int r = 0; r < 16; ++r) {
    float v = acc[r] + b;
    dst[r * HID + tid] = MISH ? mish_f(v) : v;
  }
}

// ---------------- persistent main kernel: all 1000 steps, 16 rows per block --------
__global__ __launch_bounds__(256)
void diffusion_main(const float* __restrict__ state, const float* __restrict__ x_init,
                    const float* __restrict__ w0, const float* __restrict__ b0,
                    const float* __restrict__ w1, const float* __restrict__ b1,
                    const float* __restrict__ w2, const float* __restrict__ b2,
                    const float* __restrict__ wf, const float* __restrict__ bf,
                    const float* __restrict__ tf_all, const float* __restrict__ coefs,
                    const uint32_t* __restrict__ keys, float* __restrict__ out) {
  // rows: r in [0,8) -> base+r ; r in [8,16) -> 2048+base+(r-8)
  __shared__ float s_in[16][CONC];   // [x(32) | tf(16) | state(128)]
  __shared__ float s_A[16][HID];
  __shared__ float s_B[16][HID];
  __shared__ float s_out[16][ADIM];

  const int tid = threadIdx.x;
  const int base = blockIdx.x * 8;

  for (int idx = tid; idx < 16 * ADIM; idx += 256) {
    int r = idx >> 5, c = idx & 31;
    int grow = (r < 8) ? (base + r) : (2048 + base + r - 8);
    s_in[r][c] = x_init[grow * ADIM + c];
  }
  for (int idx = tid; idx < 16 * SDIM; idx += 256) {
    int r = idx >> 7, c = idx & 127;
    int grow = (r < 8) ? (base + r) : (2048 + base + r - 8);
    s_in[r][ADIM + TDIM + c] = state[grow * SDIM + c];
  }
  __syncthreads();

  for (int t = T_STEPS - 1; t >= 0; --t) {
    {  // tf fill: 16 rows x 16 = 256 threads
      int r = tid >> 4, c = tid & 15;
      s_in[r][ADIM + c] = tf_all[t * TDIM + c];
    }
    __syncthreads();
    dense_layer<CONC, true>(w0, b0, &s_in[0][0], CONC, &s_A[0][0], tid);
    __syncthreads();
    dense_layer<HID, true>(w1, b1, &s_A[0][0], HID, &s_B[0][0], tid);
    __syncthreads();
    dense_layer<HID, true>(w2, b2, &s_B[0][0], HID, &s_A[0][0], tid);
    __syncthreads();
    {  // final: 256->32, thread = (row-quarter, dim)
      int d = tid & 31;
      int rq = tid >> 5;  // 0..7
      float bfv = bf[d];
#pragma unroll
      for (int pass = 0; pass < 2; ++pass) {
        int r = rq + pass * 8;
        float acc = bfv;
        for (int k = 0; k < HID; k += 4) {
          float4 v = *reinterpret_cast<const float4*>(&s_A[r][k]);
          acc = fmaf(v.x, wf[(k + 0) * ADIM + d], acc);
          acc = fmaf(v.y, wf[(k + 1) * ADIM + d], acc);
          acc = fmaf(v.z, wf[(k + 2) * ADIM + d], acc);
          acc = fmaf(v.w, wf[(k + 3) * ADIM + d], acc);
        }
        s_out[r][d] = acc;
      }
    }
    __syncthreads();
    {  // posterior update + JAX partitionable-threefry noise; thread -> (pair q, dim d)
      int d = tid & 31;
      int q = tid >> 5;  // 0..7
      float sr  = coefs[0 * T_STEPS + t];
      float srm = coefs[1 * T_STEPS + t];
      float c1  = coefs[2 * T_STEPS + t];
      float c2  = coefs[3 * T_STEPS + t];
      float sig = (t != 0) ? coefs[4 * T_STEPS + t] : 0.0f;
      uint32_t k0 = keys[2 * t], k1 = keys[2 * t + 1];
      uint32_t jflat = (uint32_t)((base + q) * ADIM + d);   // row base+q
      uint32_t b0n = random_bits32_partitionable(k0, k1, jflat);
      uint32_t b1n = random_bits32_partitionable(k0, k1, jflat + 65536u);  // row 2048+base+q
      float n0 = bits_to_normal(b0n);
      float n1 = bits_to_normal(b1n);
      {
        float xv = s_in[q][d];
        float eps = s_out[q][d];
        float x0v = fminf(fmaxf(sr * xv - srm * eps, -1.0f), 1.0f);
        s_in[q][d] = c1 * x0v + c2 * xv + sig * n0;
      }
      {
        float xv = s_in[8 + q][d];
        float eps = s_out[8 + q][d];
        float x0v = fminf(fmaxf(sr * xv - srm * eps, -1.0f), 1.0f);
        s_in[8 + q][d] = c1 * x0v + c2 * xv + sig * n1;
      }
    }
    // next-iteration tf-fill touches disjoint LDS ([32,48) vs [0,32)); the barrier
    // after it orders all posterior writes before dense0 reads.
  }
  __syncthreads();
  for (int idx = tid; idx < 16 * ADIM; idx += 256) {
    int r = idx >> 5, c = idx & 31;
    int grow = (r < 8) ? (base + r) : (2048 + base + r - 8);
    out[grow * ADIM + c] = fminf(fmaxf(s_in[r][c], -1.0f), 1.0f);
  }
}

// ---------------- launcher ----------------
extern "C" void kernel_launch(void* const* d_in, const int* in_sizes, int n_in,
                              void* d_out, int out_size, void* d_ws, size_t ws_size,
                              hipStream_t stream) {
  const float* state = (const float*)d_in[0];
  const float* x_init = (const float*)d_in[1];
  const float* w_t1 = (const float*)d_in[2];
  const float* b_t1 = (const float*)d_in[3];
  const float* w_t2 = (const float*)d_in[4];
  const float* b_t2 = (const float*)d_in[5];
  const float* w0 = (const float*)d_in[6];
  const float* b0 = (const float*)d_in[7];
  const float* w1 = (const float*)d_in[8];
  const float* b1 = (const float*)d_in[9];
  const float* w2 = (const float*)d_in[10];
  const float* b2 = (const float*)d_in[11];
  const float* wf = (const float*)d_in[12];
  const float* bf = (const float*)d_in[13];
  float* out = (float*)d_out;

  // workspace layout: tf_all[16000] | coefs[5000] | keys[2000 u32]  (= 92 KB)
  float* tf_all = (float*)d_ws;
  float* coefs = tf_all + T_STEPS * TDIM;
  uint32_t* keys = (uint32_t*)(coefs + 5 * T_STEPS);

  precompute_kernel<<<T_STEPS, 64, 0, stream>>>(w_t1, b_t1, w_t2, b_t2, tf_all, coefs, keys);
  diffusion_main<<<256, 256, 0, stream>>>(state, x_init, w0, b0, w1, b1, w2, b2,
                                          wf, bf, tf_all, coefs, keys, out);
}

// Round 4
// 63582.037 us; speedup vs baseline: 1.0181x; 1.0181x over previous
//
#include <hip/hip_runtime.h>
#include <stdint.h>

// ---------------- constants ----------------
#define T_STEPS 1000
#define BATCHN  4096
#define SDIM    128
#define ADIM    32
#define HID     256
#define TDIM    16
#define CONC    (ADIM + TDIM + SDIM)   // 176

// ---------------- threefry2x32 (exact JAX semantics) ----------------
__device__ __forceinline__ uint32_t rotl32(uint32_t v, int d) {
  return (v << d) | (v >> (32 - d));
}

__device__ __forceinline__ void threefry2x32(uint32_t k0, uint32_t k1,
                                             uint32_t x0, uint32_t x1,
                                             uint32_t& o0, uint32_t& o1) {
  uint32_t ks0 = k0, ks1 = k1, ks2 = k0 ^ k1 ^ 0x1BD11BDAu;
  x0 += ks0; x1 += ks1;
#define TF_ROUND(r) { x0 += x1; x1 = rotl32(x1, (r)); x1 ^= x0; }
  TF_ROUND(13) TF_ROUND(15) TF_ROUND(26) TF_ROUND(6)
  x0 += ks1; x1 += ks2 + 1u;
  TF_ROUND(17) TF_ROUND(29) TF_ROUND(16) TF_ROUND(24)
  x0 += ks2; x1 += ks0 + 2u;
  TF_ROUND(13) TF_ROUND(15) TF_ROUND(26) TF_ROUND(6)
  x0 += ks0; x1 += ks1 + 3u;
  TF_ROUND(17) TF_ROUND(29) TF_ROUND(16) TF_ROUND(24)
  x0 += ks1; x1 += ks2 + 4u;
  TF_ROUND(13) TF_ROUND(15) TF_ROUND(26) TF_ROUND(6)
  x0 += ks2; x1 += ks0 + 5u;
#undef TF_ROUND
  o0 = x0; o1 = x1;
}

// JAX partitionable threefry random_bits, bit_width=32:
//   counts = iota(u64); bits1, bits2 = threefry2x32(key, (hi32, lo32))
//   draw   = convert_element_type(bits1 ^ bits2, uint32)   <-- XOR combine
__device__ __forceinline__ uint32_t random_bits32_partitionable(uint32_t k0, uint32_t k1,
                                                               uint32_t j) {
  uint32_t o0, o1;
  threefry2x32(k0, k1, 0u, j, o0, o1);
  return o0 ^ o1;
}

// ---------------- XLA ErfInv (f32 Giles polynomial) ----------------
__device__ __forceinline__ float erfinv_f32(float x) {
  float w = -log1pf(-(x * x));
  float p;
  if (w < 5.0f) {
    w = w - 2.5f;
    p = 2.81022636e-08f;
    p = fmaf(p, w, 3.43273939e-07f);
    p = fmaf(p, w, -3.5233877e-06f);
    p = fmaf(p, w, -4.39150654e-06f);
    p = fmaf(p, w, 0.00021858087f);
    p = fmaf(p, w, -0.00125372503f);
    p = fmaf(p, w, -0.00417768164f);
    p = fmaf(p, w, 0.246640727f);
    p = fmaf(p, w, 1.50140941f);
  } else {
    w = sqrtf(w) - 3.0f;
    p = -0.000200214257f;
    p = fmaf(p, w, 0.000100950558f);
    p = fmaf(p, w, 0.00134934322f);
    p = fmaf(p, w, -0.00367342844f);
    p = fmaf(p, w, 0.00573950773f);
    p = fmaf(p, w, -0.0076224613f);
    p = fmaf(p, w, 0.00943887047f);
    p = fmaf(p, w, 1.00167406f);
    p = fmaf(p, w, 2.83297682f);
  }
  return p * x;
}

// bits -> N(0,1) exactly as jax.random.normal (threefry path)
__device__ __forceinline__ float bits_to_normal(uint32_t bits) {
  float f = __uint_as_float((bits >> 9) | 0x3F800000u) - 1.0f;   // [0,1)
  float u = f * 2.0f + (-0.99999994f);
  u = fmaxf(-0.99999994f, u);
  return 1.41421356237309515f * erfinv_f32(u);   // sqrt(2) as f32
}

// mish(x) = x * tanh(softplus(x)); jax softplus = logaddexp(x, 0)
__device__ __forceinline__ float mish_f(float x) {
  float sp = fmaxf(x, 0.0f) + log1pf(expf(-fabsf(x)));
  return x * tanhf(sp);
}

// ---------------- precompute: tf_all[1000][16], coefs[5][1000], keys[1000][2] --------
__global__ __launch_bounds__(64)
void precompute_kernel(const float* __restrict__ w_t1, const float* __restrict__ b_t1,
                       const float* __restrict__ w_t2, const float* __restrict__ b_t2,
                       float* __restrict__ tf_all, float* __restrict__ coefs,
                       uint32_t* __restrict__ keys) {
  const int i = blockIdx.x;
  const int j = threadIdx.x;
  const float tv = (float)i;
  __shared__ float hid[32];
  const float CF = (float)(-1.3157629102823120);  // -log(10000)/7
  if (j < 32) {
    float acc = b_t1[j];
#pragma unroll
    for (int k = 0; k < 16; ++k) {
      int kf = (k < 8) ? k : (k - 8);
      float fr = expf((float)kf * CF);
      float ang = tv * fr;
      float te = (k < 8) ? sinf(ang) : cosf(ang);
      acc = fmaf(te, w_t1[k * 32 + j], acc);
    }
    hid[j] = mish_f(acc);
  }
  __syncthreads();
  if (j < 16) {
    float acc = b_t2[j];
#pragma unroll
    for (int k2 = 0; k2 < 32; ++k2) acc = fmaf(hid[k2], w_t2[k2 * 16 + j], acc);
    tf_all[i * TDIM + j] = acc;
  }
  if (j == 0) {
    double t = (double)(i + 1);
    double ac  = exp(-0.1 * t / 1000.0 - 4.95 * t * t / 1.0e6);
    double acp = (i == 0) ? 1.0
        : exp(-0.1 * (t - 1.0) / 1000.0 - 4.95 * (t - 1.0) * (t - 1.0) / 1.0e6);
    double alpha = exp(-0.1 / 1000.0 - 4.95 * (2.0 * t - 1.0) / 1.0e6);
    double beta = 1.0 - alpha;
    double sr   = sqrt(1.0 / ac);
    double srm1 = sqrt(1.0 / ac - 1.0);
    double c1 = beta * sqrt(acp) / (1.0 - ac);
    double c2 = (1.0 - acp) * sqrt(alpha) / (1.0 - ac);
    double pv = beta * (1.0 - acp) / (1.0 - ac);
    double lv = log(fmax(pv, 1.0e-20));
    coefs[0 * T_STEPS + i] = (float)sr;
    coefs[1 * T_STEPS + i] = (float)srm1;
    coefs[2 * T_STEPS + i] = (float)c1;
    coefs[3 * T_STEPS + i] = (float)c2;
    float lvf = (float)lv;
    coefs[4 * T_STEPS + i] = expf(0.5f * lvf);
    uint32_t o0, o1;
    threefry2x32(0u, 1u, 0u, (uint32_t)i, o0, o1);
    keys[2 * i]     = o0;
    keys[2 * i + 1] = o1;
  }
}

// ------------- dense layer, 2 rows x 8 neurons per thread (bit-identical k-order) ----
// thread rt = tid>>5 (rows 2rt, 2rt+1), n0 = (tid&31)*8 (neurons n0..n0+7)
template <int K>
__device__ __forceinline__ void dense28(const float* __restrict__ W,
                                        const float* __restrict__ bias,
                                        const float* __restrict__ src, int sstride,
                                        float* __restrict__ dst,
                                        int rt, int n0) {
  float acc0[8], acc1[8];
#pragma unroll
  for (int j = 0; j < 8; ++j) { acc0[j] = 0.0f; acc1[j] = 0.0f; }
  const float* s0 = src + (2 * rt) * sstride;
  const float* s1 = s0 + sstride;
  const float* wp = W + n0;
#pragma unroll 2
  for (int k = 0; k < K; k += 4) {
    float4 a0 = *reinterpret_cast<const float4*>(s0 + k);
    float4 a1 = *reinterpret_cast<const float4*>(s1 + k);
    float w[4][8];
#pragma unroll
    for (int i = 0; i < 4; ++i) {
      *reinterpret_cast<float4*>(&w[i][0]) = *reinterpret_cast<const float4*>(wp + i * HID);
      *reinterpret_cast<float4*>(&w[i][4]) = *reinterpret_cast<const float4*>(wp + i * HID + 4);
    }
    float a0v[4] = {a0.x, a0.y, a0.z, a0.w};
    float a1v[4] = {a1.x, a1.y, a1.z, a1.w};
#pragma unroll
    for (int i = 0; i < 4; ++i) {
#pragma unroll
      for (int j = 0; j < 8; ++j) {
        acc0[j] = fmaf(a0v[i], w[i][j], acc0[j]);
        acc1[j] = fmaf(a1v[i], w[i][j], acc1[j]);
      }
    }
    wp += 4 * HID;
  }
  float o0[8], o1[8];
#pragma unroll
  for (int j = 0; j < 8; ++j) {
    float b = bias[n0 + j];
    o0[j] = mish_f(acc0[j] + b);
    o1[j] = mish_f(acc1[j] + b);
  }
  float* d0 = dst + (2 * rt) * HID + n0;
  float* d1 = d0 + HID;
  *reinterpret_cast<float4*>(d0)     = *reinterpret_cast<const float4*>(&o0[0]);
  *reinterpret_cast<float4*>(d0 + 4) = *reinterpret_cast<const float4*>(&o0[4]);
  *reinterpret_cast<float4*>(d1)     = *reinterpret_cast<const float4*>(&o1[0]);
  *reinterpret_cast<float4*>(d1 + 4) = *reinterpret_cast<const float4*>(&o1[4]);
}

// ---------------- persistent main kernel: all 1000 steps, 16 rows per block --------
__global__ __launch_bounds__(256)
void diffusion_main(const float* __restrict__ state, const float* __restrict__ x_init,
                    const float* __restrict__ w0, const float* __restrict__ b0,
                    const float* __restrict__ w1, const float* __restrict__ b1,
                    const float* __restrict__ w2, const float* __restrict__ b2,
                    const float* __restrict__ wf, const float* __restrict__ bf,
                    const float* __restrict__ tf_all, const float* __restrict__ coefs,
                    const uint32_t* __restrict__ keys, float* __restrict__ out) {
  // rows: r in [0,8) -> base+r ; r in [8,16) -> 2048+base+(r-8)
  __shared__ float s_in[16][CONC];   // [x(32) | tf(16) | state(128)]
  __shared__ float s_A[16][HID];
  __shared__ float s_B[16][HID];
  __shared__ float s_out[16][ADIM];

  const int tid = threadIdx.x;
  const int base = blockIdx.x * 8;
  const int rt = tid >> 5;        // 0..7
  const int n0 = (tid & 31) * 8;  // 0..248

  for (int idx = tid; idx < 16 * ADIM; idx += 256) {
    int r = idx >> 5, c = idx & 31;
    int grow = (r < 8) ? (base + r) : (2048 + base + r - 8);
    s_in[r][c] = x_init[grow * ADIM + c];
  }
  for (int idx = tid; idx < 16 * SDIM; idx += 256) {
    int r = idx >> 7, c = idx & 127;
    int grow = (r < 8) ? (base + r) : (2048 + base + r - 8);
    s_in[r][ADIM + TDIM + c] = state[grow * SDIM + c];
  }
  __syncthreads();

  for (int t = T_STEPS - 1; t >= 0; --t) {
    {  // tf fill: 16 rows x 16 = 256 threads
      int r = tid >> 4, c = tid & 15;
      s_in[r][ADIM + c] = tf_all[t * TDIM + c];
    }
    __syncthreads();
    dense28<CONC>(w0, b0, &s_in[0][0], CONC, &s_A[0][0], rt, n0);
    __syncthreads();
    dense28<HID>(w1, b1, &s_A[0][0], HID, &s_B[0][0], rt, n0);
    __syncthreads();
    dense28<HID>(w2, b2, &s_B[0][0], HID, &s_A[0][0], rt, n0);
    __syncthreads();
    {  // final: 256->32, thread = (row-quarter, dim)
      int d = tid & 31;
      int rq = tid >> 5;  // 0..7
      float bfv = bf[d];
#pragma unroll
      for (int pass = 0; pass < 2; ++pass) {
        int r = rq + pass * 8;
        float acc = bfv;
        for (int k = 0; k < HID; k += 4) {
          float4 v = *reinterpret_cast<const float4*>(&s_A[r][k]);
          acc = fmaf(v.x, wf[(k + 0) * ADIM + d], acc);
          acc = fmaf(v.y, wf[(k + 1) * ADIM + d], acc);
          acc = fmaf(v.z, wf[(k + 2) * ADIM + d], acc);
          acc = fmaf(v.w, wf[(k + 3) * ADIM + d], acc);
        }
        s_out[r][d] = acc;
      }
    }
    __syncthreads();
    {  // posterior update + JAX partitionable-threefry noise; thread -> (pair q, dim d)
      int d = tid & 31;
      int q = tid >> 5;  // 0..7
      float sr  = coefs[0 * T_STEPS + t];
      float srm = coefs[1 * T_STEPS + t];
      float c1  = coefs[2 * T_STEPS + t];
      float c2  = coefs[3 * T_STEPS + t];
      float sig = (t != 0) ? coefs[4 * T_STEPS + t] : 0.0f;
      uint32_t k0 = keys[2 * t], k1 = keys[2 * t + 1];
      uint32_t jflat = (uint32_t)((base + q) * ADIM + d);   // row base+q
      uint32_t b0n = random_bits32_partitionable(k0, k1, jflat);
      uint32_t b1n = random_bits32_partitionable(k0, k1, jflat + 65536u);  // row 2048+base+q
      float n0v = bits_to_normal(b0n);
      float n1v = bits_to_normal(b1n);
      {
        float xv = s_in[q][d];
        float eps = s_out[q][d];
        float x0v = fminf(fmaxf(sr * xv - srm * eps, -1.0f), 1.0f);
        s_in[q][d] = c1 * x0v + c2 * xv + sig * n0v;
      }
      {
        float xv = s_in[8 + q][d];
        float eps = s_out[8 + q][d];
        float x0v = fminf(fmaxf(sr * xv - srm * eps, -1.0f), 1.0f);
        s_in[8 + q][d] = c1 * x0v + c2 * xv + sig * n1v;
      }
    }
    // next-iteration tf-fill touches disjoint LDS ([32,48) vs [0,32)); the barrier
    // after it orders all posterior writes before dense0 reads.
  }
  __syncthreads();
  for (int idx = tid; idx < 16 * ADIM; idx += 256) {
    int r = idx >> 5, c = idx & 31;
    int grow = (r < 8) ? (base + r) : (2048 + base + r - 8);
    out[grow * ADIM + c] = fminf(fmaxf(s_in[r][c], -1.0f), 1.0f);
  }
}

// ---------------- launcher ----------------
extern "C" void kernel_launch(void* const* d_in, const int* in_sizes, int n_in,
                              void* d_out, int out_size, void* d_ws, size_t ws_size,
                              hipStream_t stream) {
  const float* state = (const float*)d_in[0];
  const float* x_init = (const float*)d_in[1];
  const float* w_t1 = (const float*)d_in[2];
  const float* b_t1 = (const float*)d_in[3];
  const float* w_t2 = (const float*)d_in[4];
  const float* b_t2 = (const float*)d_in[5];
  const float* w0 = (const float*)d_in[6];
  const float* b0 = (const float*)d_in[7];
  const float* w1 = (const float*)d_in[8];
  const float* b1 = (const float*)d_in[9];
  const float* w2 = (const float*)d_in[10];
  const float* b2 = (const float*)d_in[11];
  const float* wf = (const float*)d_in[12];
  const float* bf = (const float*)d_in[13];
  float* out = (float*)d_out;

  // workspace layout: tf_all[16000] | coefs[5000] | keys[2000 u32]  (= 92 KB)
  float* tf_all = (float*)d_ws;
  float* coefs = tf_all + T_STEPS * TDIM;
  uint32_t* keys = (uint32_t*)(coefs + 5 * T_STEPS);

  precompute_kernel<<<T_STEPS, 64, 0, stream>>>(w_t1, b_t1, w_t2, b_t2, tf_all, coefs, keys);
  diffusion_main<<<256, 256, 0, stream>>>(state, x_init, w0, b0, w1, b1, w2, b2,
                                          wf, bf, tf_all, coefs, keys, out);
}